// Round 4
// baseline (412.303 us; speedup 1.0000x reference)
//
#include <hip/hip_runtime.h>
#include <hip/hip_fp16.h>

// Fused 8-step diffusion: one block per (n,c) plane (256 blocks = 1 per CU).
// Each of 512 threads owns an 8-row x 4-col patch of x in registers and its
// 8x9x4 normalized |w| weights as fp16 registers (144 VGPRs), loaded from HBM
// exactly once. Row halos via 16KB LDS, column halos via wave shuffles.
//
// Round-3 failure mode: compiler capped at 128 VGPRs (4 waves/SIMD heuristic)
// -> 1/3 of wh[] spilled to scratch, reloaded every step (FETCH 362MB,
// WRITE 94MB). Fix: amdgpu_waves_per_eu(2) -> 256-VGPR budget (512/SIMD pool,
// 2 waves/SIMD), demand ~220. xr[] loaded after the weight phase to keep the
// load-phase peak (wh + a[9][4] temp) under budget.

constexpr int H = 128, W = 128, PLANE = H * W;
constexpr int NSTEP = 8;
constexpr int RPT = 8;            // rows per thread
constexpr int NRG = H / RPT;      // 16 row-groups

// build 6-wide column window (cols j0-1 .. j0+4) from a float4 row segment
#define MKWIN(D, V) do {                                                     \
    (D)[1] = (V).x; (D)[2] = (V).y; (D)[3] = (V).z; (D)[4] = (V).w;          \
    float _l = __shfl_up((V).w, 1);                                          \
    float _r = __shfl_down((V).x, 1);                                        \
    (D)[0] = (quad == 0)  ? 0.f : _l;                                        \
    (D)[5] = (quad == 31) ? 0.f : _r;                                        \
} while (0)

__global__ __launch_bounds__(512)
__attribute__((amdgpu_waves_per_eu(2)))
void diff_fused(const float* __restrict__ xin,
                const float* __restrict__ wgt,
                float* __restrict__ out)
{
    __shared__ float ldsT[NRG][W];   // top row (r0)    of each row-group
    __shared__ float ldsB[NRG][W];   // bottom row (r0+7)

    const int tid  = threadIdx.x;
    const int quad = tid & 31;       // column quad: cols 4q..4q+3
    const int rg   = tid >> 5;       // row-group 0..15
    const int j0   = quad * 4;
    const int r0   = rg * RPT;
    const size_t pbase = (size_t)blockIdx.x * PLANE;

    const float* __restrict__ xp = xin + pbase;
    const float* __restrict__ wb = wgt + pbase * 9;   // (n*576+c*9)*PLANE

    // ---- weights first (keeps load-phase register peak low):
    //      load once, |.|-normalize fp32, hold as fp16 regs ----
    __half2 wh[RPT][9][2];           // 144 VGPRs, live across whole kernel
    #pragma unroll
    for (int p = 0; p < RPT; ++p) {
        const float* wr = wb + (r0 + p) * W + j0;
        float a[9][4];
        float s0 = 0.f, s1 = 0.f, s2 = 0.f, s3 = 0.f;
        #pragma unroll
        for (int k = 0; k < 9; ++k) {
            float4 v = *reinterpret_cast<const float4*>(wr + (size_t)k * PLANE);
            a[k][0] = fabsf(v.x); a[k][1] = fabsf(v.y);
            a[k][2] = fabsf(v.z); a[k][3] = fabsf(v.w);
            s0 += a[k][0]; s1 += a[k][1]; s2 += a[k][2]; s3 += a[k][3];
        }
        s0 = 1.f / s0; s1 = 1.f / s1; s2 = 1.f / s2; s3 = 1.f / s3;
        #pragma unroll
        for (int k = 0; k < 9; ++k) {
            wh[p][k][0] = __halves2half2(__float2half_rn(a[k][0] * s0),
                                         __float2half_rn(a[k][1] * s1));
            wh[p][k][1] = __halves2half2(__float2half_rn(a[k][2] * s2),
                                         __float2half_rn(a[k][3] * s3));
        }
    }

    // ---- x patch into registers (after weights: lower peak pressure) ----
    float4 xr[RPT];
    #pragma unroll
    for (int p = 0; p < RPT; ++p)
        xr[p] = *reinterpret_cast<const float4*>(xp + (r0 + p) * W + j0);

    // ---- 8 fused steps, zero global traffic ----
    #pragma unroll 1
    for (int s = 0; s < NSTEP; ++s) {
        *reinterpret_cast<float4*>(&ldsT[rg][j0]) = xr[0];
        *reinterpret_cast<float4*>(&ldsB[rg][j0]) = xr[RPT - 1];
        __syncthreads();
        float4 up = make_float4(0.f, 0.f, 0.f, 0.f);   // global row r0-1
        float4 dn = make_float4(0.f, 0.f, 0.f, 0.f);   // global row r0+8
        if (rg > 0)       up = *reinterpret_cast<const float4*>(&ldsB[rg - 1][j0]);
        if (rg < NRG - 1) dn = *reinterpret_cast<const float4*>(&ldsT[rg + 1][j0]);
        __syncthreads();   // reads done before next step's writes

        // rotating 3-row window file; all indices constant after unroll
        float win[3][6];
        MKWIN(win[0], up);       // input row r0-1
        MKWIN(win[1], xr[0]);    // input row r0
        #pragma unroll
        for (int p = 0; p < RPT; ++p) {
            if (p < RPT - 1) { MKWIN(win[(p + 2) % 3], xr[p + 1]); }
            else             { MKWIN(win[(p + 2) % 3], dn); }
            float a0 = 0.f, a1 = 0.f, a2 = 0.f, a3 = 0.f;
            #pragma unroll
            for (int di = 0; di < 3; ++di) {
                #pragma unroll
                for (int dj = 0; dj < 3; ++dj) {
                    const int k = di * 3 + dj;
                    a0 = fmaf(__low2float (wh[p][k][0]), win[(p + di) % 3][dj + 0], a0);
                    a1 = fmaf(__high2float(wh[p][k][0]), win[(p + di) % 3][dj + 1], a1);
                    a2 = fmaf(__low2float (wh[p][k][1]), win[(p + di) % 3][dj + 2], a2);
                    a3 = fmaf(__high2float(wh[p][k][1]), win[(p + di) % 3][dj + 3], a3);
                }
            }
            xr[p] = make_float4(a0, a1, a2, a3);   // old xr[p] fully consumed
        }
    }

    // ---- store (coalesced float4) ----
    float* __restrict__ op = out + pbase;
    #pragma unroll
    for (int p = 0; p < RPT; ++p)
        *reinterpret_cast<float4*>(op + (r0 + p) * W + j0) = xr[p];
}

extern "C" void kernel_launch(void* const* d_in, const int* in_sizes, int n_in,
                              void* d_out, int out_size, void* d_ws, size_t ws_size,
                              hipStream_t stream)
{
    const float* x = (const float*)d_in[0];
    const float* w = (const float*)d_in[1];
    float* out = (float*)d_out;
    (void)d_ws; (void)ws_size; (void)in_sizes; (void)n_in; (void)out_size;

    diff_fused<<<dim3(4 * 64), dim3(512), 0, stream>>>(x, w, out);
}

// Round 5
// 407.846 us; speedup vs baseline: 1.0109x; 1.0109x over previous
//
#include <hip/hip_runtime.h>
#include <hip/hip_fp16.h>

// Fused 8-step diffusion: one block per (n,c) plane (256 blocks = 1 per CU).
// Each of 512 threads owns an 8-row x 4-col patch of x in registers and its
// 8x9x4 normalized |w| weights as fp16 registers (144 VGPRs), loaded from HBM
// exactly once. Row halos via 16KB LDS, column halos via wave shuffles.
//
// Register-budget history:
//   R3: __launch_bounds__(512,2)        -> VGPR capped 128, wh[] spilled
//   R4: amdgpu_waves_per_eu(2) min-only -> still 128 (hint, scheduler still
//       targets 4 waves/EU and spills to reach it; FETCH 394MB WRITE 157MB)
//   R5: amdgpu_waves_per_eu(2,2) min AND max -> occupancy can't exceed
//       2 waves/EU, so allocator has no reason to stay under 256 VGPRs.
//       Demand ~224; block is 8 waves = 2/EU anyway, so no occupancy loss.

constexpr int H = 128, W = 128, PLANE = H * W;
constexpr int NSTEP = 8;
constexpr int RPT = 8;            // rows per thread
constexpr int NRG = H / RPT;      // 16 row-groups

// build 6-wide column window (cols j0-1 .. j0+4) from a float4 row segment
#define MKWIN(D, V) do {                                                     \
    (D)[1] = (V).x; (D)[2] = (V).y; (D)[3] = (V).z; (D)[4] = (V).w;          \
    float _l = __shfl_up((V).w, 1);                                          \
    float _r = __shfl_down((V).x, 1);                                        \
    (D)[0] = (quad == 0)  ? 0.f : _l;                                        \
    (D)[5] = (quad == 31) ? 0.f : _r;                                        \
} while (0)

__global__ __launch_bounds__(512)
__attribute__((amdgpu_waves_per_eu(2, 2)))
void diff_fused(const float* __restrict__ xin,
                const float* __restrict__ wgt,
                float* __restrict__ out)
{
    __shared__ float ldsT[NRG][W];   // top row (r0)    of each row-group
    __shared__ float ldsB[NRG][W];   // bottom row (r0+7)

    const int tid  = threadIdx.x;
    const int quad = tid & 31;       // column quad: cols 4q..4q+3
    const int rg   = tid >> 5;       // row-group 0..15
    const int j0   = quad * 4;
    const int r0   = rg * RPT;
    const size_t pbase = (size_t)blockIdx.x * PLANE;

    const float* __restrict__ xp = xin + pbase;
    const float* __restrict__ wb = wgt + pbase * 9;   // (n*576+c*9)*PLANE

    // ---- weights first (keeps load-phase register peak low):
    //      load once, |.|-normalize fp32, hold as fp16 regs ----
    __half2 wh[RPT][9][2];           // 144 VGPRs, live across whole kernel
    #pragma unroll
    for (int p = 0; p < RPT; ++p) {
        const float* wr = wb + (r0 + p) * W + j0;
        float a[9][4];
        float s0 = 0.f, s1 = 0.f, s2 = 0.f, s3 = 0.f;
        #pragma unroll
        for (int k = 0; k < 9; ++k) {
            float4 v = *reinterpret_cast<const float4*>(wr + (size_t)k * PLANE);
            a[k][0] = fabsf(v.x); a[k][1] = fabsf(v.y);
            a[k][2] = fabsf(v.z); a[k][3] = fabsf(v.w);
            s0 += a[k][0]; s1 += a[k][1]; s2 += a[k][2]; s3 += a[k][3];
        }
        s0 = 1.f / s0; s1 = 1.f / s1; s2 = 1.f / s2; s3 = 1.f / s3;
        #pragma unroll
        for (int k = 0; k < 9; ++k) {
            wh[p][k][0] = __halves2half2(__float2half_rn(a[k][0] * s0),
                                         __float2half_rn(a[k][1] * s1));
            wh[p][k][1] = __halves2half2(__float2half_rn(a[k][2] * s2),
                                         __float2half_rn(a[k][3] * s3));
        }
    }

    // ---- x patch into registers (after weights: lower peak pressure) ----
    float4 xr[RPT];
    #pragma unroll
    for (int p = 0; p < RPT; ++p)
        xr[p] = *reinterpret_cast<const float4*>(xp + (r0 + p) * W + j0);

    // ---- 8 fused steps, zero global traffic ----
    #pragma unroll 1
    for (int s = 0; s < NSTEP; ++s) {
        *reinterpret_cast<float4*>(&ldsT[rg][j0]) = xr[0];
        *reinterpret_cast<float4*>(&ldsB[rg][j0]) = xr[RPT - 1];
        __syncthreads();
        float4 up = make_float4(0.f, 0.f, 0.f, 0.f);   // global row r0-1
        float4 dn = make_float4(0.f, 0.f, 0.f, 0.f);   // global row r0+8
        if (rg > 0)       up = *reinterpret_cast<const float4*>(&ldsB[rg - 1][j0]);
        if (rg < NRG - 1) dn = *reinterpret_cast<const float4*>(&ldsT[rg + 1][j0]);
        __syncthreads();   // reads done before next step's writes

        // rotating 3-row window file; all indices constant after unroll
        float win[3][6];
        MKWIN(win[0], up);       // input row r0-1
        MKWIN(win[1], xr[0]);    // input row r0
        #pragma unroll
        for (int p = 0; p < RPT; ++p) {
            if (p < RPT - 1) { MKWIN(win[(p + 2) % 3], xr[p + 1]); }
            else             { MKWIN(win[(p + 2) % 3], dn); }
            float a0 = 0.f, a1 = 0.f, a2 = 0.f, a3 = 0.f;
            #pragma unroll
            for (int di = 0; di < 3; ++di) {
                #pragma unroll
                for (int dj = 0; dj < 3; ++dj) {
                    const int k = di * 3 + dj;
                    a0 = fmaf(__low2float (wh[p][k][0]), win[(p + di) % 3][dj + 0], a0);
                    a1 = fmaf(__high2float(wh[p][k][0]), win[(p + di) % 3][dj + 1], a1);
                    a2 = fmaf(__low2float (wh[p][k][1]), win[(p + di) % 3][dj + 2], a2);
                    a3 = fmaf(__high2float(wh[p][k][1]), win[(p + di) % 3][dj + 3], a3);
                }
            }
            xr[p] = make_float4(a0, a1, a2, a3);   // old xr[p] fully consumed
        }
    }

    // ---- store (coalesced float4) ----
    float* __restrict__ op = out + pbase;
    #pragma unroll
    for (int p = 0; p < RPT; ++p)
        *reinterpret_cast<float4*>(op + (r0 + p) * W + j0) = xr[p];
}

extern "C" void kernel_launch(void* const* d_in, const int* in_sizes, int n_in,
                              void* d_out, int out_size, void* d_ws, size_t ws_size,
                              hipStream_t stream)
{
    const float* x = (const float*)d_in[0];
    const float* w = (const float*)d_in[1];
    float* out = (float*)d_out;
    (void)d_ws; (void)ws_size; (void)in_sizes; (void)n_in; (void)out_size;

    diff_fused<<<dim3(4 * 64), dim3(512), 0, stream>>>(x, w, out);
}

// Round 6
// 269.489 us; speedup vs baseline: 1.5299x; 1.5134x over previous
//
#include <hip/hip_runtime.h>
#include <hip/hip_fp16.h>

// Fused 8-step diffusion, redesigned to fit the empirically hard 128-VGPR cap
// (R3/R4/R5: every attempt to unlock a 256-VGPR budget failed; VGPR_Count
// pinned at 128 with ~380MB scratch spill traffic).
//
// Layout: 512 blocks = 2 per (n,c) plane, 512 threads each (2 blocks/CU).
// Each block covers an 80-row window: 64 owned rows + 8-row halo each side,
// computed REDUNDANTLY so blocks never communicate. Wrongness from the
// missing neighbor row propagates 1 row/step; after 8 steps it reaches only
// the first unowned row. Pad rows (gr<0 or >=128) are forced to 0 each step.
// Per thread: 5 rows x 4 cols. Weights: 4 rows in regs (72 VGPRs fp16),
// 5th row in LDS (36KB uint2, lane-consecutive -> 2-way aliasing = free).
// Register demand ~118 < 128 -> no spill.

constexpr int H = 128, W = 128, PLANE = H * W;
constexpr int NSTEP = 8;
constexpr int RPT = 5;            // rows per thread (80-row window / 16 rg)
constexpr int NRG = 16;
constexpr int HALO = 8;
constexpr int OWN = 64;

// 6-wide column window (cols j0-1 .. j0+4) from a float4 row segment
#define MKWIN(D, V) do {                                                     \
    (D)[1] = (V).x; (D)[2] = (V).y; (D)[3] = (V).z; (D)[4] = (V).w;          \
    float _l = __shfl_up((V).w, 1);                                          \
    float _r = __shfl_down((V).x, 1);                                        \
    (D)[0] = (quad == 0)  ? 0.f : _l;                                        \
    (D)[5] = (quad == 31) ? 0.f : _r;                                        \
} while (0)

__global__ __launch_bounds__(512)
void diff_fused(const float* __restrict__ xin,
                const float* __restrict__ wgt,
                float* __restrict__ out)
{
    __shared__ float ldsT[NRG][W];      // each rg's top row    (8 KB)
    __shared__ float ldsB[NRG][W];      // each rg's bottom row (8 KB)
    __shared__ uint2 whL[9][512];       // p=4 weights, fp16x4/thread (36 KB)

    const int tid   = threadIdx.x;
    const int quad  = tid & 31;         // cols 4q..4q+3
    const int rg    = tid >> 5;         // 0..15
    const int j0    = quad * 4;
    const int plane = blockIdx.x >> 1;
    const int half  = blockIdx.x & 1;
    const int rbase = half * OWN - HALO;        // window start row
    const int r0    = rbase + rg * RPT;         // this thread's first row
    const size_t pbase = (size_t)plane * PLANE;

    const float* __restrict__ xp = xin + pbase;
    const float* __restrict__ wb = wgt + pbase * 9;

    // ---- weights: load once, |.|-normalize fp32, pack fp16.
    //      rows p=0..3 -> registers; p=4 -> LDS ----
    __half2 wh[RPT - 1][9][2];          // 72 VGPRs
    #pragma unroll
    for (int p = 0; p < RPT; ++p) {
        const int  gr  = r0 + p;
        const bool inr = (unsigned)gr < (unsigned)H;
        const float* wr = wb + gr * W + j0;
        float a[9][4];
        float s0 = 0.f, s1 = 0.f, s2 = 0.f, s3 = 0.f;
        #pragma unroll
        for (int k = 0; k < 9; ++k) {
            float4 v = make_float4(1.f, 1.f, 1.f, 1.f);  // dummy for pad rows
            if (inr) v = *reinterpret_cast<const float4*>(wr + (size_t)k * PLANE);
            a[k][0] = fabsf(v.x); a[k][1] = fabsf(v.y);
            a[k][2] = fabsf(v.z); a[k][3] = fabsf(v.w);
            s0 += a[k][0]; s1 += a[k][1]; s2 += a[k][2]; s3 += a[k][3];
        }
        s0 = 1.f / s0; s1 = 1.f / s1; s2 = 1.f / s2; s3 = 1.f / s3;
        #pragma unroll
        for (int k = 0; k < 9; ++k) {
            __half2 h0 = __halves2half2(__float2half_rn(a[k][0] * s0),
                                        __float2half_rn(a[k][1] * s1));
            __half2 h1 = __halves2half2(__float2half_rn(a[k][2] * s2),
                                        __float2half_rn(a[k][3] * s3));
            if (p < RPT - 1) {
                wh[p][k][0] = h0;
                wh[p][k][1] = h1;
            } else {
                whL[k][tid] = make_uint2(__builtin_bit_cast(unsigned int, h0),
                                         __builtin_bit_cast(unsigned int, h1));
            }
        }
    }

    // ---- x window into registers (pad rows -> 0) ----
    float4 xr[RPT];
    #pragma unroll
    for (int p = 0; p < RPT; ++p) {
        const int gr = r0 + p;
        xr[p] = make_float4(0.f, 0.f, 0.f, 0.f);
        if ((unsigned)gr < (unsigned)H)
            xr[p] = *reinterpret_cast<const float4*>(xp + gr * W + j0);
    }
    __syncthreads();   // whL writes visible before step loop reads

    // ---- 8 fused steps, zero global traffic ----
    #pragma unroll 1
    for (int s = 0; s < NSTEP; ++s) {
        *reinterpret_cast<float4*>(&ldsT[rg][j0]) = xr[0];
        *reinterpret_cast<float4*>(&ldsB[rg][j0]) = xr[RPT - 1];
        __syncthreads();
        float4 up = make_float4(0.f, 0.f, 0.f, 0.f);   // row r0-1
        float4 dn = make_float4(0.f, 0.f, 0.f, 0.f);   // row r0+5
        if (rg > 0)       up = *reinterpret_cast<const float4*>(&ldsB[rg - 1][j0]);
        if (rg < NRG - 1) dn = *reinterpret_cast<const float4*>(&ldsT[rg + 1][j0]);
        __syncthreads();   // reads done before next step's writes

        float win[3][6];
        MKWIN(win[0], up);       // input row r0-1
        MKWIN(win[1], xr[0]);    // input row r0
        #pragma unroll
        for (int p = 0; p < RPT; ++p) {
            if (p < RPT - 1) { MKWIN(win[(p + 2) % 3], xr[p + 1]); }
            else             { MKWIN(win[(p + 2) % 3], dn); }
            float a0 = 0.f, a1 = 0.f, a2 = 0.f, a3 = 0.f;
            #pragma unroll
            for (int di = 0; di < 3; ++di) {
                #pragma unroll
                for (int dj = 0; dj < 3; ++dj) {
                    const int k = di * 3 + dj;
                    __half2 w0, w1;
                    if (p < RPT - 1) { w0 = wh[p][k][0]; w1 = wh[p][k][1]; }
                    else {
                        uint2 lv = whL[k][tid];
                        w0 = __builtin_bit_cast(__half2, lv.x);
                        w1 = __builtin_bit_cast(__half2, lv.y);
                    }
                    a0 = fmaf(__low2float (w0), win[(p + di) % 3][dj + 0], a0);
                    a1 = fmaf(__high2float(w0), win[(p + di) % 3][dj + 1], a1);
                    a2 = fmaf(__low2float (w1), win[(p + di) % 3][dj + 2], a2);
                    a3 = fmaf(__high2float(w1), win[(p + di) % 3][dj + 3], a3);
                }
            }
            xr[p] = make_float4(a0, a1, a2, a3);
        }
        // re-impose zero padding (keeps pad rows 0 every step)
        #pragma unroll
        for (int p = 0; p < RPT; ++p) {
            const int gr = r0 + p;
            if ((unsigned)gr >= (unsigned)H)
                xr[p] = make_float4(0.f, 0.f, 0.f, 0.f);
        }
    }

    // ---- store owned rows only (coalesced float4) ----
    float* __restrict__ op = out + pbase;
    #pragma unroll
    for (int p = 0; p < RPT; ++p) {
        const int gr = r0 + p;
        const int lr = gr - half * OWN;
        if ((unsigned)lr < (unsigned)OWN)
            *reinterpret_cast<float4*>(op + gr * W + j0) = xr[p];
    }
}

extern "C" void kernel_launch(void* const* d_in, const int* in_sizes, int n_in,
                              void* d_out, int out_size, void* d_ws, size_t ws_size,
                              hipStream_t stream)
{
    const float* x = (const float*)d_in[0];
    const float* w = (const float*)d_in[1];
    float* out = (float*)d_out;
    (void)d_ws; (void)ws_size; (void)in_sizes; (void)n_in; (void)out_size;

    // 512 blocks = 2 per plane (4n x 64c), 512 threads
    diff_fused<<<dim3(2 * 4 * 64), dim3(512), 0, stream>>>(x, w, out);
}